// Round 19
// baseline (744.479 us; speedup 1.0000x reference)
//
#include <hip/hip_runtime.h>
#include <hip/hip_bf16.h>
#include <stdint.h>

typedef __attribute__((ext_vector_type(8))) short short8;
typedef __attribute__((ext_vector_type(8))) _Float16 half8;
typedef __attribute__((ext_vector_type(4))) float f32x4;

#define HSTR ((size_t)131072 * 32)   // head-major stride: [16][131072][32]

__device__ __forceinline__ unsigned short f2h(float f) {
  union { _Float16 h; unsigned short u; } c;
  c.h = (_Float16)f;
  return c.u;
}
__device__ __forceinline__ float h2f(unsigned short u) {
  union { _Float16 h; unsigned short u; } c;
  c.u = u;
  return (float)c.h;
}
__device__ __forceinline__ void gload_lds16(const void* g, void* l) {
  __builtin_amdgcn_global_load_lds(
      (const __attribute__((address_space(1))) unsigned int*)g,
      (__attribute__((address_space(3))) unsigned int*)l, 16, 0, 0);
}

// ---------------- prep kernels ----------------

__global__ __launch_bounds__(256) void cast_f16(const float* __restrict__ in,
                                                unsigned short* __restrict__ out) {
  const size_t total = (size_t)131072 * 512 / 8;
  size_t stride = (size_t)gridDim.x * 256;
  for (size_t i = blockIdx.x * 256 + threadIdx.x; i < total; i += stride) {
    f32x4 f0 = *(const f32x4*)(in + i * 8);
    f32x4 f1 = *(const f32x4*)(in + i * 8 + 4);
    short8 o;
#pragma unroll
    for (int e = 0; e < 4; e++) {
      o[e] = (short)f2h(f0[e]);
      o[4 + e] = (short)f2h(f1[e]);
    }
    *(short8*)(out + i * 8) = o;
  }
}

__global__ __launch_bounds__(256) void transpose_cast(const float* __restrict__ in,
                                                      unsigned short* __restrict__ out,
                                                      int K, int N) {
  __shared__ float tile[32][33];
  int nb = N / 32;
  int bx = blockIdx.x % nb, by = blockIdx.x / nb;
  int tx = threadIdx.x & 31, ty = threadIdx.x >> 5;  // 32 x 8
#pragma unroll
  for (int r = 0; r < 32; r += 8)
    tile[ty + r][tx] = in[(size_t)(by * 32 + ty + r) * N + bx * 32 + tx];
  __syncthreads();
#pragma unroll
  for (int r = 0; r < 32; r += 8)
    out[(size_t)(bx * 32 + ty + r) * K + by * 32 + tx] = f2h(tile[tx][ty + r]);
}

__device__ __forceinline__ float cpb_coord(int a) {
  float v = (float)(a - 7) * (8.0f / 7.0f);
  float s = (v > 0.f) ? 1.f : ((v < 0.f) ? -1.f : 0.f);
  return s * log2f(fabsf(v) + 1.f) * (1.f / 3.f);
}

__global__ __launch_bounds__(64) void cpb_mlp(const float* __restrict__ w1,
                                              const float* __restrict__ b1,
                                              const float* __restrict__ w2,
                                              float* __restrict__ t_out) {
  int e = blockIdx.x;
  int dy = e / 15, dx = e % 15;
  float in0 = cpb_coord(dy), in1 = cpb_coord(dx);
  float acc[16];
#pragma unroll
  for (int o = 0; o < 16; ++o) acc[o] = 0.f;
  for (int u = threadIdx.x; u < 512; u += 64) {
    float hsum = fmaxf(in0 * w1[u] + in1 * w1[512 + u] + b1[u], 0.f);
#pragma unroll
    for (int o = 0; o < 16; ++o) acc[o] += hsum * w2[u * 16 + o];
  }
#pragma unroll
  for (int o = 0; o < 16; ++o) {
    float v = acc[o];
    v += __shfl_xor(v, 1);  v += __shfl_xor(v, 2);  v += __shfl_xor(v, 4);
    v += __shfl_xor(v, 8);  v += __shfl_xor(v, 16); v += __shfl_xor(v, 32);
    acc[o] = v;
  }
  if (threadIdx.x == 0)
#pragma unroll
    for (int o = 0; o < 16; ++o) t_out[e * 16 + o] = acc[o];
}

// bias[h][i][j] = 16*sigmoid(t[idx(i,j)][h])
__global__ __launch_bounds__(256) void bias_kernel(const float* __restrict__ t,
                                                   float* __restrict__ bias) {
  int idx = blockIdx.x * 256 + threadIdx.x;  // 65536
  int j = idx & 63, i = (idx >> 6) & 63, h = idx >> 12;
  int dy = (i >> 3) - (j >> 3) + 7;
  int dx = (i & 7) - (j & 7) + 7;
  float v = t[(dy * 15 + dx) * 16 + h];
  bias[idx] = 16.f / (1.f + expf(-v));
}

// ---------------- K1: qkv GEMM (256x256, BK=32, 3-buffer 2-ahead counted-vmcnt) ----------------
__global__ __launch_bounds__(512, 1) void qkv_gemm(const unsigned short* __restrict__ xh,
                                                   const unsigned short* __restrict__ Wt,
                                                   const float* __restrict__ bvec,
                                                   unsigned short* __restrict__ qout,
                                                   unsigned short* __restrict__ kout,
                                                   unsigned short* __restrict__ vout) {
  // LDS 96 KB: A[3][256][32] fp16 elems [0,24576), B[3][256][32] elems [24576,49152)
  __shared__ __align__(16) short smem[49152];
  const int bid = (blockIdx.x & 7) * 384 + (blockIdx.x >> 3);
  const int nt = bid % 6;
  const int mt = bid / 6;
  const int m0 = mt * 256, n0 = nt * 256;
  const int t = threadIdx.x;
  const int l = t & 63, wid = t >> 6;
  const int wm = wid >> 2, wn = wid & 3;   // 2 x 4 waves, wave-tile 128x64
  const int fr = l & 15, fg = l >> 4;

  f32x4 acc[8][4];
#pragma unroll
  for (int i = 0; i < 8; i++)
#pragma unroll
    for (int j = 0; j < 4; j++) acc[i][j] = f32x4{0.f, 0.f, 0.f, 0.f};

  auto STAGE = [&](int bsel, int kt) {
#pragma unroll
    for (int it = 0; it < 2; ++it) {
      int flat = it * 512 + t;           // 0..1023
      int row = flat >> 2, s = flat & 3;
      int g = s ^ (row & 3);
      gload_lds16(xh + (size_t)(m0 + row) * 512 + kt * 32 + g * 8,
                  &smem[bsel * 8192 + flat * 8]);
      gload_lds16(Wt + (size_t)(n0 + row) * 512 + kt * 32 + g * 8,
                  &smem[24576 + bsel * 8192 + flat * 8]);
    }
  };

  STAGE(0, 0);
  STAGE(1, 1);
  __builtin_amdgcn_sched_barrier(0);

  for (int kt = 0; kt < 16; ++kt) {
    const int cur = kt % 3;
    if (kt < 14) STAGE((kt + 2) % 3, kt + 2);
    __builtin_amdgcn_sched_barrier(0);
    if (kt < 14)       asm volatile("s_waitcnt vmcnt(8)" ::: "memory");
    else if (kt == 14) asm volatile("s_waitcnt vmcnt(4)" ::: "memory");
    else               asm volatile("s_waitcnt vmcnt(0)" ::: "memory");
    __builtin_amdgcn_sched_barrier(0);
    __builtin_amdgcn_s_barrier();
    __builtin_amdgcn_sched_barrier(0);
    {
      const short* Ab = &smem[cur * 8192];
      const short* Bb = &smem[24576 + cur * 8192];
      half8 bfr[4];
#pragma unroll
      for (int j = 0; j < 4; ++j) {
        int row = wn * 64 + j * 16 + fr;
        bfr[j] = *(const half8*)&Bb[row * 32 + ((fg ^ (row & 3)) << 3)];
      }
#pragma unroll
      for (int i = 0; i < 8; ++i) {
        int rowA = wm * 128 + i * 16 + fr;
        half8 a0 = *(const half8*)&Ab[rowA * 32 + ((fg ^ (rowA & 3)) << 3)];
#pragma unroll
        for (int j = 0; j < 4; ++j)
          acc[i][j] = __builtin_amdgcn_mfma_f32_16x16x32_f16(a0, bfr[j], acc[i][j], 0, 0, 0);
      }
    }
    __builtin_amdgcn_sched_barrier(0);
    __builtin_amdgcn_s_barrier();
    __builtin_amdgcn_sched_barrier(0);
  }

  // epilogue: two 128-row halves, LDS fp16 bounce (+bias) -> head-major stores
  unsigned short* dst;
  int g0;
  if (nt < 2)      { dst = qout; g0 = nt * 8; }
  else if (nt < 4) { dst = kout; g0 = (nt - 2) * 8; }
  else             { dst = vout; g0 = (nt - 4) * 8; }
#pragma unroll
  for (int hh = 0; hh < 2; ++hh) {
    if (hh) __syncthreads();
    if (wm == hh) {
#pragma unroll
      for (int i = 0; i < 8; ++i)
#pragma unroll
        for (int j = 0; j < 4; ++j) {
          int col = wn * 64 + j * 16 + fr;
          float bb = bvec[n0 + col];
#pragma unroll
          for (int r = 0; r < 4; ++r)
            smem[(i * 16 + fg * 4 + r) * 256 + col] = (short)f2h(acc[i][j][r] + bb);
        }
    }
    __syncthreads();
#pragma unroll
    for (int it = 0; it < 8; ++it) {
      int flat = it * 512 + t;
      int row = flat >> 5, c32 = flat & 31;
      *(short8*)(dst + (size_t)(g0 + (c32 >> 2)) * HSTR +
                 (size_t)(m0 + hh * 128 + row) * 32 + (c32 & 3) * 8) =
          *(short8*)&smem[row * 256 + c32 * 8];
    }
  }
}

// ---------------- K2: fused window attention (LDS-overlaid: 14.1 KB pool) ----------------
// pool layout: [0,2048) qs | [2048,4096) ks | [4608,6912) vt | [6912,7040) invs
// P (4x16x72 = 4608 shorts) OVERLAYS [0,4608) after qs/ks dead; out-bounce overlays [0,2048).
__global__ __launch_bounds__(256) void attn_kernel(const unsigned short* __restrict__ qws,
                                                   const unsigned short* __restrict__ kws,
                                                   const unsigned short* __restrict__ vws,
                                                   const float* __restrict__ bias,
                                                   const float* __restrict__ mask,
                                                   const float* __restrict__ logit_scale,
                                                   unsigned short* __restrict__ aout) {
  const int blk = (blockIdx.x & 7) * 4096 + (blockIdx.x >> 3);
  const int h = blk >> 11;        // 16 heads
  const int b = blk & 2047;       // 2048 windows
  const int wmi = b & 255;        // mask window index
  const int t = threadIdx.x, l = t & 63, w = t >> 6;

  __shared__ __align__(16) short pool[7040];
  short* qs   = pool;           // [0,2048)
  short* ks   = pool + 2048;    // [2048,4096)
  short* plds = pool;           // [0,4608) overlay
  short* vt   = pool + 4608;    // [4608,6912)
  float* invs = (float*)(pool + 6912);

  const float scale = __expf(fminf(logit_scale[h], 4.6051702f));

  {
    const int r = t >> 2, c4 = t & 3;
    const size_t base = (size_t)h * HSTR + (size_t)(b * 64 + r) * 32 + c4 * 8;
    {
      uint4 raw = *(const uint4*)(qws + base);
      unsigned int rr[4] = {raw.x, raw.y, raw.z, raw.w};
      float f[8];
#pragma unroll
      for (int e = 0; e < 4; e++) {
        f[2 * e]     = h2f((unsigned short)(rr[e] & 0xffff));
        f[2 * e + 1] = h2f((unsigned short)(rr[e] >> 16));
      }
      float ss = 0.f;
#pragma unroll
      for (int e = 0; e < 8; e++) ss += f[e] * f[e];
      ss += __shfl_xor(ss, 1);
      ss += __shfl_xor(ss, 2);
      float inv = 1.f / fmaxf(sqrtf(ss), 1e-12f);
      short8 o;
#pragma unroll
      for (int e = 0; e < 8; e++) o[e] = (short)f2h(f[e] * inv);
      *(short8*)&qs[r * 32 + c4 * 8] = o;
    }
    {
      uint4 raw = *(const uint4*)(kws + base);
      unsigned int rr[4] = {raw.x, raw.y, raw.z, raw.w};
      float f[8];
#pragma unroll
      for (int e = 0; e < 4; e++) {
        f[2 * e]     = h2f((unsigned short)(rr[e] & 0xffff));
        f[2 * e + 1] = h2f((unsigned short)(rr[e] >> 16));
      }
      float ss = 0.f;
#pragma unroll
      for (int e = 0; e < 8; e++) ss += f[e] * f[e];
      ss += __shfl_xor(ss, 1);
      ss += __shfl_xor(ss, 2);
      float inv = 1.f / fmaxf(sqrtf(ss), 1e-12f);
      short8 o;
#pragma unroll
      for (int e = 0; e < 8; e++) o[e] = (short)f2h(f[e] * inv);
      *(short8*)&ks[r * 32 + c4 * 8] = o;
    }
    {
      uint4 raw = *(const uint4*)(vws + base);
      unsigned int rr[4] = {raw.x, raw.y, raw.z, raw.w};
#pragma unroll
      for (int e2 = 0; e2 < 4; e2++) {
        vt[(c4 * 8 + 2 * e2 + 0) * 72 + r] = (short)(rr[e2] & 0xffff);
        vt[(c4 * 8 + 2 * e2 + 1) * 72 + r] = (short)(rr[e2] >> 16);
      }
    }
  }
  __syncthreads();

  const int fr = l & 15, fg = l >> 4;
  half8 bq = *(half8*)&qs[(w * 16 + fr) * 32 + fg * 8];

  f32x4 st[4];
#pragma unroll
  for (int kt = 0; kt < 4; kt++) {
    half8 ak = *(half8*)&ks[(kt * 16 + fr) * 32 + fg * 8];
    st[kt] = __builtin_amdgcn_mfma_f32_16x16x32_f16(ak, bq, f32x4{0.f, 0.f, 0.f, 0.f}, 0, 0, 0);
  }
  const int q = w * 16 + fr;
  const int kbase = fg * 4;
  float sv[16];
  float mx = -1e30f;
#pragma unroll
  for (int kt = 0; kt < 4; kt++) {
    f32x4 b4 = *(const f32x4*)&bias[(size_t)(h * 64 + q) * 64 + kt * 16 + kbase];
    f32x4 m4 = *(const f32x4*)&mask[(size_t)(wmi * 64 + q) * 64 + kt * 16 + kbase];
#pragma unroll
    for (int j = 0; j < 4; j++) {
      float xv = st[kt][j] * scale + b4[j] + m4[j];
      sv[kt * 4 + j] = xv;
      mx = fmaxf(mx, xv);
    }
  }
  mx = fmaxf(mx, __shfl_xor(mx, 16));
  mx = fmaxf(mx, __shfl_xor(mx, 32));
  float sum = 0.f;
#pragma unroll
  for (int i2 = 0; i2 < 16; i2++) {
    float p = __expf(sv[i2] - mx);
    sv[i2] = p;
    sum += p;
  }
  sum += __shfl_xor(sum, 16);
  sum += __shfl_xor(sum, 32);

  __syncthreads();   // all QK^T ds_reads of qs/ks complete before P overlays them

  short* pl = &plds[w * 16 * 72];
#pragma unroll
  for (int kt = 0; kt < 4; kt++)
#pragma unroll
    for (int j = 0; j < 4; j += 2) {
      unsigned int pack = (unsigned int)f2h(sv[kt * 4 + j]) |
                          ((unsigned int)f2h(sv[kt * 4 + j + 1]) << 16);
      *(unsigned int*)&pl[fr * 72 + kt * 16 + kbase + j] = pack;
    }
  if (fg == 0) invs[q] = 1.f / sum;
  __syncthreads();

  // PV: read ALL fragments into regs, barrier, then compute + overlay out-bounce
  half8 pa0  = *(half8*)&pl[fr * 72 + fg * 8];
  half8 pa1  = *(half8*)&pl[fr * 72 + 32 + fg * 8];
  half8 bv00 = *(half8*)&vt[fr * 72 + fg * 8];
  half8 bv01 = *(half8*)&vt[fr * 72 + 32 + fg * 8];
  half8 bv10 = *(half8*)&vt[(16 + fr) * 72 + fg * 8];
  half8 bv11 = *(half8*)&vt[(16 + fr) * 72 + 32 + fg * 8];
  const int qo = w * 16 + fg * 4;
  float inv0 = invs[qo], inv1 = invs[qo + 1], inv2 = invs[qo + 2], inv3 = invs[qo + 3];
  __syncthreads();   // all P/vt/invs reads complete before out-bounce overlays [0,2048)

  {
    f32x4 o0 = f32x4{0.f, 0.f, 0.f, 0.f};
    o0 = __builtin_amdgcn_mfma_f32_16x16x32_f16(pa0, bv00, o0, 0, 0, 0);
    o0 = __builtin_amdgcn_mfma_f32_16x16x32_f16(pa1, bv01, o0, 0, 0, 0);
    f32x4 o1 = f32x4{0.f, 0.f, 0.f, 0.f};
    o1 = __builtin_amdgcn_mfma_f32_16x16x32_f16(pa0, bv10, o1, 0, 0, 0);
    o1 = __builtin_amdgcn_mfma_f32_16x16x32_f16(pa1, bv11, o1, 0, 0, 0);
    float iv[4] = {inv0, inv1, inv2, inv3};
#pragma unroll
    for (int r2 = 0; r2 < 4; r2++) {
      pool[(qo + r2) * 32 + fr]      = (short)f2h(o0[r2] * iv[r2]);
      pool[(qo + r2) * 32 + 16 + fr] = (short)f2h(o1[r2] * iv[r2]);
    }
  }
  __syncthreads();
  {
    const int row = t >> 2, c = t & 3;
    *(short8*)(aout + (size_t)h * HSTR + (size_t)(b * 64 + row) * 32 + c * 8) =
        *(short8*)&pool[row * 32 + c * 8];
  }
}

// ---------------- K3: output projection (3-buffer 2-ahead counted-vmcnt, swizzled) ----------------
__global__ __launch_bounds__(256) void proj_gemm(const unsigned short* __restrict__ A,
                                                 const unsigned short* __restrict__ Wt,
                                                 const float* __restrict__ bvec,
                                                 float* __restrict__ out) {
  // LDS 48 KB: A[3][128][32] elems [0,12288), B[3][128][32] elems [12288,24576)
  __shared__ __align__(16) short smem[24576];
  const int bid = (blockIdx.x & 7) * 512 + (blockIdx.x >> 3);
  const int nt = bid & 3;
  const int mt = bid >> 2;
  const int m0 = mt * 128, n0 = nt * 128;
  const int t = threadIdx.x;
  const int l = t & 63, w = t >> 6;
  const int wm = w >> 1, wn = w & 1;
  const int fr = l & 15, fg = l >> 4;

  f32x4 acc[4][4];
#pragma unroll
  for (int i = 0; i < 4; i++)
#pragma unroll
    for (int j = 0; j < 4; j++) acc[i][j] = f32x4{0.f, 0.f, 0.f, 0.f};

  auto STAGE = [&](int bsel, int kt) {
#pragma unroll
    for (int it = 0; it < 2; ++it) {
      int flat = it * 256 + t;           // 0..511
      int row = flat >> 2, s = flat & 3;
      int g = s ^ (row & 3);
      gload_lds16(A + (size_t)kt * HSTR + (size_t)(m0 + row) * 32 + g * 8,
                  &smem[bsel * 4096 + flat * 8]);
      gload_lds16(Wt + (size_t)(n0 + row) * 512 + kt * 32 + g * 8,
                  &smem[12288 + bsel * 4096 + flat * 8]);
    }
  };

  STAGE(0, 0);
  STAGE(1, 1);
  __builtin_amdgcn_sched_barrier(0);

  for (int kt = 0; kt < 16; ++kt) {
    const int cur = kt % 3;
    if (kt < 14) STAGE((kt + 2) % 3, kt + 2);
    __builtin_amdgcn_sched_barrier(0);
    if (kt < 14)       asm volatile("s_waitcnt vmcnt(8)" ::: "memory");
    else if (kt == 14) asm volatile("s_waitcnt vmcnt(4)" ::: "memory");
    else               asm volatile("s_waitcnt vmcnt(0)" ::: "memory");
    __builtin_amdgcn_sched_barrier(0);
    __builtin_amdgcn_s_barrier();
    __builtin_amdgcn_sched_barrier(0);
    {
      const short* Ab = &smem[cur * 4096];
      const short* Bb = &smem[12288 + cur * 4096];
      half8 bfr[4];
#pragma unroll
      for (int j = 0; j < 4; ++j) {
        int row = wn * 64 + j * 16 + fr;
        bfr[j] = *(const half8*)&Bb[row * 32 + ((fg ^ (row & 3)) << 3)];
      }
#pragma unroll
      for (int i = 0; i < 4; ++i) {
        int rowA = wm * 64 + i * 16 + fr;
        half8 a0 = *(const half8*)&Ab[rowA * 32 + ((fg ^ (rowA & 3)) << 3)];
#pragma unroll
        for (int j = 0; j < 4; ++j)
          acc[i][j] = __builtin_amdgcn_mfma_f32_16x16x32_f16(a0, bfr[j], acc[i][j], 0, 0, 0);
      }
    }
    __builtin_amdgcn_sched_barrier(0);
    __builtin_amdgcn_s_barrier();
    __builtin_amdgcn_sched_barrier(0);
  }

  // epilogue: fp32 bounce in two 64-row halves (32 KB each)
  float* bounce = (float*)smem;
#pragma unroll
  for (int half = 0; half < 2; ++half) {
    if (half) __syncthreads();
    if (wm == half) {
#pragma unroll
      for (int j = 0; j < 4; j++) {
        int col = wn * 64 + j * 16 + fr;
        float bb = bvec[n0 + col];
#pragma unroll
        for (int i = 0; i < 4; i++) {
          int row0 = i * 16 + fg * 4;
#pragma unroll
          for (int r = 0; r < 4; r++)
            bounce[(row0 + r) * 128 + col] = acc[i][j][r] + bb;
        }
      }
    }
    __syncthreads();
#pragma unroll
    for (int it = 0; it < 8; ++it) {
      int flat = it * 256 + t;
      int row = flat >> 5, c4 = flat & 31;
      *(f32x4*)(out + (size_t)(m0 + half * 64 + row) * 512 + n0 + c4 * 4) =
          *(f32x4*)&bounce[row * 128 + c4 * 4];
    }
    __syncthreads();
  }
}

extern "C" void kernel_launch(void* const* d_in, const int* in_sizes, int n_in,
                              void* d_out, int out_size, void* d_ws, size_t ws_size,
                              hipStream_t stream) {
  const float* x           = (const float*)d_in[0];
  const float* mask        = (const float*)d_in[1];
  const float* qkv_w       = (const float*)d_in[2];
  const float* qkv_b       = (const float*)d_in[3];
  const float* logit_scale = (const float*)d_in[4];
  const float* cpb_w1      = (const float*)d_in[5];
  const float* cpb_b1      = (const float*)d_in[6];
  const float* cpb_w2      = (const float*)d_in[7];
  const float* proj_w      = (const float*)d_in[8];
  const float* proj_b      = (const float*)d_in[9];
  (void)in_sizes; (void)n_in; (void)out_size; (void)ws_size;

  char* p = (char*)d_ws;
  unsigned short* Wqkv_t  = (unsigned short*)p; p += (size_t)1536 * 512 * 2;
  unsigned short* Wproj_t = (unsigned short*)p; p += (size_t)512 * 512 * 2;
  float* t_cpb            = (float*)p;          p += (size_t)225 * 16 * 4;   // 14400 (16B-mult)
  float* biasb            = (float*)p;          p += (size_t)16 * 64 * 64 * 4;
  unsigned short* xh      = (unsigned short*)p; p += (size_t)131072 * 512 * 2;
  unsigned short* qbuf    = (unsigned short*)p; p += (size_t)131072 * 512 * 2;
  unsigned short* kbuf    = (unsigned short*)p; p += (size_t)131072 * 512 * 2;
  unsigned short* vbuf    = (unsigned short*)p; p += (size_t)131072 * 512 * 2;
  unsigned short* abuf    = (unsigned short*)p; p += (size_t)131072 * 512 * 2;

  cast_f16<<<2048, 256, 0, stream>>>(x, xh);
  transpose_cast<<<768, 256, 0, stream>>>(qkv_w, Wqkv_t, 512, 1536);
  transpose_cast<<<256, 256, 0, stream>>>(proj_w, Wproj_t, 512, 512);
  cpb_mlp<<<225, 64, 0, stream>>>(cpb_w1, cpb_b1, cpb_w2, t_cpb);
  bias_kernel<<<256, 256, 0, stream>>>(t_cpb, biasb);
  qkv_gemm<<<3072, 512, 0, stream>>>(xh, Wqkv_t, qkv_b, qbuf, kbuf, vbuf);
  attn_kernel<<<32768, 256, 0, stream>>>(qbuf, kbuf, vbuf, biasb, mask, logit_scale, abuf);
  proj_gemm<<<4096, 256, 0, stream>>>(abuf, Wproj_t, proj_b, (float*)d_out);
}

// Round 20
// 713.781 us; speedup vs baseline: 1.0430x; 1.0430x over previous
//
#include <hip/hip_runtime.h>
#include <hip/hip_bf16.h>
#include <stdint.h>

typedef __attribute__((ext_vector_type(8))) short short8;
typedef __attribute__((ext_vector_type(8))) _Float16 half8;
typedef __attribute__((ext_vector_type(4))) float f32x4;

#define HSTR ((size_t)131072 * 32)   // head-major stride: [16][131072][32]

__device__ __forceinline__ unsigned short f2h(float f) {
  union { _Float16 h; unsigned short u; } c;
  c.h = (_Float16)f;
  return c.u;
}
__device__ __forceinline__ float h2f(unsigned short u) {
  union { _Float16 h; unsigned short u; } c;
  c.u = u;
  return (float)c.h;
}
__device__ __forceinline__ void gload_lds16(const void* g, void* l) {
  __builtin_amdgcn_global_load_lds(
      (const __attribute__((address_space(1))) unsigned int*)g,
      (__attribute__((address_space(3))) unsigned int*)l, 16, 0, 0);
}

// ---------------- prep kernels ----------------

__global__ __launch_bounds__(256) void cast_f16(const float* __restrict__ in,
                                                unsigned short* __restrict__ out) {
  const size_t total = (size_t)131072 * 512 / 8;
  size_t stride = (size_t)gridDim.x * 256;
  for (size_t i = blockIdx.x * 256 + threadIdx.x; i < total; i += stride) {
    f32x4 f0 = *(const f32x4*)(in + i * 8);
    f32x4 f1 = *(const f32x4*)(in + i * 8 + 4);
    short8 o;
#pragma unroll
    for (int e = 0; e < 4; e++) {
      o[e] = (short)f2h(f0[e]);
      o[4 + e] = (short)f2h(f1[e]);
    }
    *(short8*)(out + i * 8) = o;
  }
}

__global__ __launch_bounds__(256) void transpose_cast(const float* __restrict__ in,
                                                      unsigned short* __restrict__ out,
                                                      int K, int N) {
  __shared__ float tile[32][33];
  int nb = N / 32;
  int bx = blockIdx.x % nb, by = blockIdx.x / nb;
  int tx = threadIdx.x & 31, ty = threadIdx.x >> 5;  // 32 x 8
#pragma unroll
  for (int r = 0; r < 32; r += 8)
    tile[ty + r][tx] = in[(size_t)(by * 32 + ty + r) * N + bx * 32 + tx];
  __syncthreads();
#pragma unroll
  for (int r = 0; r < 32; r += 8)
    out[(size_t)(bx * 32 + ty + r) * K + by * 32 + tx] = f2h(tile[tx][ty + r]);
}

__device__ __forceinline__ float cpb_coord(int a) {
  float v = (float)(a - 7) * (8.0f / 7.0f);
  float s = (v > 0.f) ? 1.f : ((v < 0.f) ? -1.f : 0.f);
  return s * log2f(fabsf(v) + 1.f) * (1.f / 3.f);
}

__global__ __launch_bounds__(64) void cpb_mlp(const float* __restrict__ w1,
                                              const float* __restrict__ b1,
                                              const float* __restrict__ w2,
                                              float* __restrict__ t_out) {
  int e = blockIdx.x;
  int dy = e / 15, dx = e % 15;
  float in0 = cpb_coord(dy), in1 = cpb_coord(dx);
  float acc[16];
#pragma unroll
  for (int o = 0; o < 16; ++o) acc[o] = 0.f;
  for (int u = threadIdx.x; u < 512; u += 64) {
    float hsum = fmaxf(in0 * w1[u] + in1 * w1[512 + u] + b1[u], 0.f);
#pragma unroll
    for (int o = 0; o < 16; ++o) acc[o] += hsum * w2[u * 16 + o];
  }
#pragma unroll
  for (int o = 0; o < 16; ++o) {
    float v = acc[o];
    v += __shfl_xor(v, 1);  v += __shfl_xor(v, 2);  v += __shfl_xor(v, 4);
    v += __shfl_xor(v, 8);  v += __shfl_xor(v, 16); v += __shfl_xor(v, 32);
    acc[o] = v;
  }
  if (threadIdx.x == 0)
#pragma unroll
    for (int o = 0; o < 16; ++o) t_out[e * 16 + o] = acc[o];
}

// bias[h][i][j] = 16*sigmoid(t[idx(i,j)][h])
__global__ __launch_bounds__(256) void bias_kernel(const float* __restrict__ t,
                                                   float* __restrict__ bias) {
  int idx = blockIdx.x * 256 + threadIdx.x;  // 65536
  int j = idx & 63, i = (idx >> 6) & 63, h = idx >> 12;
  int dy = (i >> 3) - (j >> 3) + 7;
  int dx = (i & 7) - (j & 7) + 7;
  float v = t[(dy * 15 + dx) * 16 + h];
  bias[idx] = 16.f / (1.f + expf(-v));
}

// ---------------- K1: qkv GEMM (256x256, BK=32, 3-buffer 2-ahead counted-vmcnt) ----------------
__global__ __launch_bounds__(512, 1) void qkv_gemm(const unsigned short* __restrict__ xh,
                                                   const unsigned short* __restrict__ Wt,
                                                   const float* __restrict__ bvec,
                                                   unsigned short* __restrict__ qout,
                                                   unsigned short* __restrict__ kout,
                                                   unsigned short* __restrict__ vout) {
  // LDS 96 KB: A[3][256][32] fp16 elems [0,24576), B[3][256][32] elems [24576,49152)
  __shared__ __align__(16) short smem[49152];
  const int bid = (blockIdx.x & 7) * 384 + (blockIdx.x >> 3);
  const int nt = bid % 6;
  const int mt = bid / 6;
  const int m0 = mt * 256, n0 = nt * 256;
  const int t = threadIdx.x;
  const int l = t & 63, wid = t >> 6;
  const int wm = wid >> 2, wn = wid & 3;   // 2 x 4 waves, wave-tile 128x64
  const int fr = l & 15, fg = l >> 4;

  f32x4 acc[8][4];
#pragma unroll
  for (int i = 0; i < 8; i++)
#pragma unroll
    for (int j = 0; j < 4; j++) acc[i][j] = f32x4{0.f, 0.f, 0.f, 0.f};

  auto STAGE = [&](int bsel, int kt) {
#pragma unroll
    for (int it = 0; it < 2; ++it) {
      int flat = it * 512 + t;           // 0..1023
      int row = flat >> 2, s = flat & 3;
      int g = s ^ (row & 3);
      gload_lds16(xh + (size_t)(m0 + row) * 512 + kt * 32 + g * 8,
                  &smem[bsel * 8192 + flat * 8]);
      gload_lds16(Wt + (size_t)(n0 + row) * 512 + kt * 32 + g * 8,
                  &smem[24576 + bsel * 8192 + flat * 8]);
    }
  };

  STAGE(0, 0);
  STAGE(1, 1);
  __builtin_amdgcn_sched_barrier(0);

  for (int kt = 0; kt < 16; ++kt) {
    const int cur = kt % 3;
    if (kt < 14) STAGE((kt + 2) % 3, kt + 2);
    __builtin_amdgcn_sched_barrier(0);
    if (kt < 14)       asm volatile("s_waitcnt vmcnt(8)" ::: "memory");
    else if (kt == 14) asm volatile("s_waitcnt vmcnt(4)" ::: "memory");
    else               asm volatile("s_waitcnt vmcnt(0)" ::: "memory");
    __builtin_amdgcn_sched_barrier(0);
    __builtin_amdgcn_s_barrier();
    __builtin_amdgcn_sched_barrier(0);
    {
      const short* Ab = &smem[cur * 8192];
      const short* Bb = &smem[24576 + cur * 8192];
      half8 bfr[4];
#pragma unroll
      for (int j = 0; j < 4; ++j) {
        int row = wn * 64 + j * 16 + fr;
        bfr[j] = *(const half8*)&Bb[row * 32 + ((fg ^ (row & 3)) << 3)];
      }
#pragma unroll
      for (int i = 0; i < 8; ++i) {
        int rowA = wm * 128 + i * 16 + fr;
        half8 a0 = *(const half8*)&Ab[rowA * 32 + ((fg ^ (rowA & 3)) << 3)];
#pragma unroll
        for (int j = 0; j < 4; ++j)
          acc[i][j] = __builtin_amdgcn_mfma_f32_16x16x32_f16(a0, bfr[j], acc[i][j], 0, 0, 0);
      }
    }
    __builtin_amdgcn_sched_barrier(0);
    __builtin_amdgcn_s_barrier();
    __builtin_amdgcn_sched_barrier(0);
  }

  // epilogue: two 128-row halves, LDS fp16 bounce (+bias) -> head-major stores
  unsigned short* dst;
  int g0;
  if (nt < 2)      { dst = qout; g0 = nt * 8; }
  else if (nt < 4) { dst = kout; g0 = (nt - 2) * 8; }
  else             { dst = vout; g0 = (nt - 4) * 8; }
#pragma unroll
  for (int hh = 0; hh < 2; ++hh) {
    if (hh) __syncthreads();
    if (wm == hh) {
#pragma unroll
      for (int i = 0; i < 8; ++i)
#pragma unroll
        for (int j = 0; j < 4; ++j) {
          int col = wn * 64 + j * 16 + fr;
          float bb = bvec[n0 + col];
#pragma unroll
          for (int r = 0; r < 4; ++r)
            smem[(i * 16 + fg * 4 + r) * 256 + col] = (short)f2h(acc[i][j][r] + bb);
        }
    }
    __syncthreads();
#pragma unroll
    for (int it = 0; it < 8; ++it) {
      int flat = it * 512 + t;
      int row = flat >> 5, c32 = flat & 31;
      *(short8*)(dst + (size_t)(g0 + (c32 >> 2)) * HSTR +
                 (size_t)(m0 + hh * 128 + row) * 32 + (c32 & 3) * 8) =
          *(short8*)&smem[row * 256 + c32 * 8];
    }
  }
}

// ---------------- K2: fused window attention (head-major q/k/v; norm in-kernel) ----------------
__global__ __launch_bounds__(256) void attn_kernel(const unsigned short* __restrict__ qws,
                                                   const unsigned short* __restrict__ kws,
                                                   const unsigned short* __restrict__ vws,
                                                   const float* __restrict__ bias,
                                                   const float* __restrict__ mask,
                                                   const float* __restrict__ logit_scale,
                                                   unsigned short* __restrict__ aout) {
  const int blk = (blockIdx.x & 7) * 4096 + (blockIdx.x >> 3);
  const int h = blk >> 11;        // 16 heads
  const int b = blk & 2047;       // 2048 windows
  const int wmi = b & 255;        // mask window index
  const int t = threadIdx.x, l = t & 63, w = t >> 6;

  __shared__ __align__(16) short qs[64 * 32], ks[64 * 32];
  __shared__ __align__(16) short vt[32 * 72];
  __shared__ __align__(16) short plds[4 * 16 * 72];
  __shared__ float invs[64];

  const float scale = __expf(fminf(logit_scale[h], 4.6051702f));

  {
    const int r = t >> 2, c4 = t & 3;
    const size_t base = (size_t)h * HSTR + (size_t)(b * 64 + r) * 32 + c4 * 8;
    {
      uint4 raw = *(const uint4*)(qws + base);
      unsigned int rr[4] = {raw.x, raw.y, raw.z, raw.w};
      float f[8];
#pragma unroll
      for (int e = 0; e < 4; e++) {
        f[2 * e]     = h2f((unsigned short)(rr[e] & 0xffff));
        f[2 * e + 1] = h2f((unsigned short)(rr[e] >> 16));
      }
      float ss = 0.f;
#pragma unroll
      for (int e = 0; e < 8; e++) ss += f[e] * f[e];
      ss += __shfl_xor(ss, 1);
      ss += __shfl_xor(ss, 2);
      float inv = 1.f / fmaxf(sqrtf(ss), 1e-12f);
      short8 o;
#pragma unroll
      for (int e = 0; e < 8; e++) o[e] = (short)f2h(f[e] * inv);
      *(short8*)&qs[r * 32 + c4 * 8] = o;
    }
    {
      uint4 raw = *(const uint4*)(kws + base);
      unsigned int rr[4] = {raw.x, raw.y, raw.z, raw.w};
      float f[8];
#pragma unroll
      for (int e = 0; e < 4; e++) {
        f[2 * e]     = h2f((unsigned short)(rr[e] & 0xffff));
        f[2 * e + 1] = h2f((unsigned short)(rr[e] >> 16));
      }
      float ss = 0.f;
#pragma unroll
      for (int e = 0; e < 8; e++) ss += f[e] * f[e];
      ss += __shfl_xor(ss, 1);
      ss += __shfl_xor(ss, 2);
      float inv = 1.f / fmaxf(sqrtf(ss), 1e-12f);
      short8 o;
#pragma unroll
      for (int e = 0; e < 8; e++) o[e] = (short)f2h(f[e] * inv);
      *(short8*)&ks[r * 32 + c4 * 8] = o;
    }
    {
      uint4 raw = *(const uint4*)(vws + base);
      unsigned int rr[4] = {raw.x, raw.y, raw.z, raw.w};
#pragma unroll
      for (int e2 = 0; e2 < 4; e2++) {
        vt[(c4 * 8 + 2 * e2 + 0) * 72 + r] = (short)(rr[e2] & 0xffff);
        vt[(c4 * 8 + 2 * e2 + 1) * 72 + r] = (short)(rr[e2] >> 16);
      }
    }
  }
  __syncthreads();

  const int fr = l & 15, fg = l >> 4;
  half8 bq = *(half8*)&qs[(w * 16 + fr) * 32 + fg * 8];

  f32x4 st[4];
#pragma unroll
  for (int kt = 0; kt < 4; kt++) {
    half8 ak = *(half8*)&ks[(kt * 16 + fr) * 32 + fg * 8];
    st[kt] = __builtin_amdgcn_mfma_f32_16x16x32_f16(ak, bq, f32x4{0.f, 0.f, 0.f, 0.f}, 0, 0, 0);
  }
  const int q = w * 16 + fr;
  const int kbase = fg * 4;
  float sv[16];
  float mx = -1e30f;
#pragma unroll
  for (int kt = 0; kt < 4; kt++) {
    f32x4 b4 = *(const f32x4*)&bias[(size_t)(h * 64 + q) * 64 + kt * 16 + kbase];
    f32x4 m4 = *(const f32x4*)&mask[(size_t)(wmi * 64 + q) * 64 + kt * 16 + kbase];
#pragma unroll
    for (int j = 0; j < 4; j++) {
      float xv = st[kt][j] * scale + b4[j] + m4[j];
      sv[kt * 4 + j] = xv;
      mx = fmaxf(mx, xv);
    }
  }
  mx = fmaxf(mx, __shfl_xor(mx, 16));
  mx = fmaxf(mx, __shfl_xor(mx, 32));
  float sum = 0.f;
#pragma unroll
  for (int i2 = 0; i2 < 16; i2++) {
    float p = __expf(sv[i2] - mx);
    sv[i2] = p;
    sum += p;
  }
  sum += __shfl_xor(sum, 16);
  sum += __shfl_xor(sum, 32);

  short* pl = &plds[w * 16 * 72];
#pragma unroll
  for (int kt = 0; kt < 4; kt++)
#pragma unroll
    for (int j = 0; j < 4; j += 2) {
      unsigned int pack = (unsigned int)f2h(sv[kt * 4 + j]) |
                          ((unsigned int)f2h(sv[kt * 4 + j + 1]) << 16);
      *(unsigned int*)&pl[fr * 72 + kt * 16 + kbase + j] = pack;
    }
  if (fg == 0) invs[q] = 1.f / sum;
  __syncthreads();

  half8 pa0 = *(half8*)&pl[fr * 72 + fg * 8];
  half8 pa1 = *(half8*)&pl[fr * 72 + 32 + fg * 8];
#pragma unroll
  for (int nt2 = 0; nt2 < 2; nt2++) {
    half8 bv0 = *(half8*)&vt[(nt2 * 16 + fr) * 72 + fg * 8];
    half8 bv1 = *(half8*)&vt[(nt2 * 16 + fr) * 72 + 32 + fg * 8];
    f32x4 o = f32x4{0.f, 0.f, 0.f, 0.f};
    o = __builtin_amdgcn_mfma_f32_16x16x32_f16(pa0, bv0, o, 0, 0, 0);
    o = __builtin_amdgcn_mfma_f32_16x16x32_f16(pa1, bv1, o, 0, 0, 0);
    const int qo = w * 16 + fg * 4;
    const int hd = nt2 * 16 + fr;
#pragma unroll
    for (int r2 = 0; r2 < 4; r2++) {
      float vv = o[r2] * invs[qo + r2];
      qs[(qo + r2) * 32 + hd] = (short)f2h(vv);
    }
  }
  __syncthreads();
  {
    const int row = t >> 2, c = t & 3;
    *(short8*)(aout + (size_t)h * HSTR + (size_t)(b * 64 + row) * 32 + c * 8) =
        *(short8*)&qs[row * 32 + c * 8];
  }
}

// ---------------- K3: output projection (3-buffer 2-ahead counted-vmcnt, swizzled) ----------------
__global__ __launch_bounds__(256) void proj_gemm(const unsigned short* __restrict__ A,
                                                 const unsigned short* __restrict__ Wt,
                                                 const float* __restrict__ bvec,
                                                 float* __restrict__ out) {
  // LDS 48 KB: A[3][128][32] elems [0,12288), B[3][128][32] elems [12288,24576)
  __shared__ __align__(16) short smem[24576];
  const int bid = (blockIdx.x & 7) * 512 + (blockIdx.x >> 3);
  const int nt = bid & 3;
  const int mt = bid >> 2;
  const int m0 = mt * 128, n0 = nt * 128;
  const int t = threadIdx.x;
  const int l = t & 63, w = t >> 6;
  const int wm = w >> 1, wn = w & 1;
  const int fr = l & 15, fg = l >> 4;

  f32x4 acc[4][4];
#pragma unroll
  for (int i = 0; i < 4; i++)
#pragma unroll
    for (int j = 0; j < 4; j++) acc[i][j] = f32x4{0.f, 0.f, 0.f, 0.f};

  auto STAGE = [&](int bsel, int kt) {
#pragma unroll
    for (int it = 0; it < 2; ++it) {
      int flat = it * 256 + t;           // 0..511
      int row = flat >> 2, s = flat & 3;
      int g = s ^ (row & 3);
      gload_lds16(A + (size_t)kt * HSTR + (size_t)(m0 + row) * 32 + g * 8,
                  &smem[bsel * 4096 + flat * 8]);
      gload_lds16(Wt + (size_t)(n0 + row) * 512 + kt * 32 + g * 8,
                  &smem[12288 + bsel * 4096 + flat * 8]);
    }
  };

  STAGE(0, 0);
  STAGE(1, 1);
  __builtin_amdgcn_sched_barrier(0);

  for (int kt = 0; kt < 16; ++kt) {
    const int cur = kt % 3;
    if (kt < 14) STAGE((kt + 2) % 3, kt + 2);
    __builtin_amdgcn_sched_barrier(0);
    if (kt < 14)       asm volatile("s_waitcnt vmcnt(8)" ::: "memory");
    else if (kt == 14) asm volatile("s_waitcnt vmcnt(4)" ::: "memory");
    else               asm volatile("s_waitcnt vmcnt(0)" ::: "memory");
    __builtin_amdgcn_sched_barrier(0);
    __builtin_amdgcn_s_barrier();
    __builtin_amdgcn_sched_barrier(0);
    {
      const short* Ab = &smem[cur * 4096];
      const short* Bb = &smem[12288 + cur * 4096];
      half8 bfr[4];
#pragma unroll
      for (int j = 0; j < 4; ++j) {
        int row = wn * 64 + j * 16 + fr;
        bfr[j] = *(const half8*)&Bb[row * 32 + ((fg ^ (row & 3)) << 3)];
      }
#pragma unroll
      for (int i = 0; i < 4; ++i) {
        int rowA = wm * 64 + i * 16 + fr;
        half8 a0 = *(const half8*)&Ab[rowA * 32 + ((fg ^ (rowA & 3)) << 3)];
#pragma unroll
        for (int j = 0; j < 4; ++j)
          acc[i][j] = __builtin_amdgcn_mfma_f32_16x16x32_f16(a0, bfr[j], acc[i][j], 0, 0, 0);
      }
    }
    __builtin_amdgcn_sched_barrier(0);
    __builtin_amdgcn_s_barrier();
    __builtin_amdgcn_sched_barrier(0);
  }

  // epilogue: fp32 bounce in two 64-row halves (32 KB each)
  float* bounce = (float*)smem;
#pragma unroll
  for (int half = 0; half < 2; ++half) {
    if (half) __syncthreads();
    if (wm == half) {
#pragma unroll
      for (int j = 0; j < 4; j++) {
        int col = wn * 64 + j * 16 + fr;
        float bb = bvec[n0 + col];
#pragma unroll
        for (int i = 0; i < 4; i++) {
          int row0 = i * 16 + fg * 4;
#pragma unroll
          for (int r = 0; r < 4; r++)
            bounce[(row0 + r) * 128 + col] = acc[i][j][r] + bb;
        }
      }
    }
    __syncthreads();
#pragma unroll
    for (int it = 0; it < 8; ++it) {
      int flat = it * 256 + t;
      int row = flat >> 5, c4 = flat & 31;
      *(f32x4*)(out + (size_t)(m0 + half * 64 + row) * 512 + n0 + c4 * 4) =
          *(f32x4*)&bounce[row * 128 + c4 * 4];
    }
    __syncthreads();
  }
}

extern "C" void kernel_launch(void* const* d_in, const int* in_sizes, int n_in,
                              void* d_out, int out_size, void* d_ws, size_t ws_size,
                              hipStream_t stream) {
  const float* x           = (const float*)d_in[0];
  const float* mask        = (const float*)d_in[1];
  const float* qkv_w       = (const float*)d_in[2];
  const float* qkv_b       = (const float*)d_in[3];
  const float* logit_scale = (const float*)d_in[4];
  const float* cpb_w1      = (const float*)d_in[5];
  const float* cpb_b1      = (const float*)d_in[6];
  const float* cpb_w2      = (const float*)d_in[7];
  const float* proj_w      = (const float*)d_in[8];
  const float* proj_b      = (const float*)d_in[9];
  (void)in_sizes; (void)n_in; (void)out_size; (void)ws_size;

  char* p = (char*)d_ws;
  unsigned short* Wqkv_t  = (unsigned short*)p; p += (size_t)1536 * 512 * 2;
  unsigned short* Wproj_t = (unsigned short*)p; p += (size_t)512 * 512 * 2;
  float* t_cpb            = (float*)p;          p += (size_t)225 * 16 * 4;   // 14400 (16B-mult)
  float* biasb            = (float*)p;          p += (size_t)16 * 64 * 64 * 4;
  unsigned short* xh      = (unsigned short*)p; p += (size_t)131072 * 512 * 2;
  unsigned short* qbuf    = (unsigned short*)p; p += (size_t)131072 * 512 * 2;
  unsigned short* kbuf    = (unsigned short*)p; p += (size_t)131072 * 512 * 2;
  unsigned short* vbuf    = (unsigned short*)p; p += (size_t)131072 * 512 * 2;
  unsigned short* abuf    = (unsigned short*)p; p += (size_t)131072 * 512 * 2;

  cast_f16<<<2048, 256, 0, stream>>>(x, xh);
  transpose_cast<<<768, 256, 0, stream>>>(qkv_w, Wqkv_t, 512, 1536);
  transpose_cast<<<256, 256, 0, stream>>>(proj_w, Wproj_t, 512, 512);
  cpb_mlp<<<225, 64, 0, stream>>>(cpb_w1, cpb_b1, cpb_w2, t_cpb);
  bias_kernel<<<256, 256, 0, stream>>>(t_cpb, biasb);
  qkv_gemm<<<3072, 512, 0, stream>>>(xh, Wqkv_t, qkv_b, qbuf, kbuf, vbuf);
  attn_kernel<<<32768, 256, 0, stream>>>(qbuf, kbuf, vbuf, biasb, mask, logit_scale, abuf);
  proj_gemm<<<4096, 256, 0, stream>>>(abuf, Wproj_t, proj_b, (float*)d_out);
}